// Round 1
// baseline (95.501 us; speedup 1.0000x reference)
//
#include <hip/hip_runtime.h>

#define TPB 256
#define PTS_PER_BLOCK 512

// Fused StandardPershomReadout: 3 rational-hat reductions.
// out (B=128, 3*64): part0 from h_0 (D=2), part1/2 from h_{0,1}_ess (D=1).
// f(d) = 1/(1+d) - 1/(1+|R-d|)  ==  (|R-d| - d) / ((1+d)*(1+|R-d|))
// (common-denominator form: 1 rcp instead of 2; rcp is quarter-rate trans)
__global__ __launch_bounds__(TPB) void pershom_kernel(
    const float* __restrict__ h0,  const float* __restrict__ m0,
    const float* __restrict__ h0e, const float* __restrict__ m0e,
    const float* __restrict__ h1e, const float* __restrict__ m1e,
    const float* __restrict__ c0,  const float* __restrict__ r0,
    const float* __restrict__ c0e, const float* __restrict__ r0e,
    const float* __restrict__ c1e, const float* __restrict__ r1e,
    float* __restrict__ out)
{
    __shared__ float4 pts[PTS_PER_BLOCK];   // (x, y, mask, pad)
    __shared__ float  partial[4][64];

    const int bid = blockIdx.x;
    const int tid = threadIdx.x;
    const int k   = tid & 63;   // center index owned by this thread
    const int sub = tid >> 6;   // wave id: each wave sweeps a 128-pt strip

    const float* h; const float* m; const float* cen; const float* rad;
    int outidx, D;
    if (bid < 1024) {                       // part 0: 128 b * 8 slices
        int b = bid >> 3, p0 = (bid & 7) * PTS_PER_BLOCK;
        h = h0 + (size_t)(b * 4096 + p0) * 2; m = m0 + b * 4096 + p0;
        cen = c0; rad = r0; outidx = b * 192 + k; D = 2;
    } else if (bid < 1280) {                // part 1: 128 b * 2 slices
        int t = bid - 1024;
        int b = t >> 1, p0 = (t & 1) * PTS_PER_BLOCK;
        h = h0e + b * 1024 + p0; m = m0e + b * 1024 + p0;
        cen = c0e; rad = r0e; outidx = b * 192 + 64 + k; D = 1;
    } else {                                // part 2: 128 b * 2 slices
        int t = bid - 1280;
        int b = t >> 1, p0 = (t & 1) * PTS_PER_BLOCK;
        h = h1e + b * 1024 + p0; m = m1e + b * 1024 + p0;
        cen = c1e; rad = r1e; outidx = b * 192 + 128 + k; D = 1;
    }

    // Stage 512 points (x, y, mask) into LDS, coalesced.
    if (D == 2) {
        const float2* src = (const float2*)h;
        for (int i = tid; i < PTS_PER_BLOCK; i += TPB) {
            float2 xy = src[i];
            pts[i] = make_float4(xy.x, xy.y, m[i], 0.f);
        }
    } else {
        for (int i = tid; i < PTS_PER_BLOCK; i += TPB) {
            pts[i] = make_float4(h[i], 0.f, m[i], 0.f);
        }
    }

    // Per-thread center (registers) + radius.
    float cx, cy;
    if (D == 2) { cx = cen[2 * k]; cy = cen[2 * k + 1]; }
    else        { cx = cen[k];     cy = 0.f; }
    const float R = fabsf(rad[0]);

    __syncthreads();

    // Each wave (uniform sub) sweeps its 128-point strip; every lane reads the
    // SAME LDS address per iteration -> broadcast, conflict-free.
    float acc = 0.f;
    const int pstart = sub * (PTS_PER_BLOCK / 4);
    #pragma unroll 4
    for (int i = 0; i < PTS_PER_BLOCK / 4; ++i) {
        float4 pt = pts[pstart + i];
        float d   = fabsf(pt.x - cx) + fabsf(pt.y - cy);
        float at  = fabsf(R - d);
        float num = at - d;
        float den = (1.f + d) * (1.f + at);
        acc += pt.z * num * __builtin_amdgcn_rcpf(den);
    }

    partial[sub][k] = acc;
    __syncthreads();
    if (tid < 64) {
        float s = partial[0][tid] + partial[1][tid]
                + partial[2][tid] + partial[3][tid];
        atomicAdd(&out[outidx], s);   // k == tid here, outidx already has +k
    }
}

extern "C" void kernel_launch(void* const* d_in, const int* in_sizes, int n_in,
                              void* d_out, int out_size, void* d_ws, size_t ws_size,
                              hipStream_t stream) {
    const float* h0  = (const float*)d_in[0];
    const float* m0  = (const float*)d_in[1];
    const float* h0e = (const float*)d_in[2];
    const float* m0e = (const float*)d_in[3];
    const float* h1e = (const float*)d_in[4];
    const float* m1e = (const float*)d_in[5];
    const float* c0  = (const float*)d_in[6];
    const float* r0  = (const float*)d_in[7];
    const float* c0e = (const float*)d_in[8];
    const float* r0e = (const float*)d_in[9];
    const float* c1e = (const float*)d_in[10];
    const float* r1e = (const float*)d_in[11];
    float* out = (float*)d_out;

    // d_out is poisoned (0xAA) before every launch; we accumulate with atomics.
    hipMemsetAsync(out, 0, (size_t)out_size * sizeof(float), stream);

    dim3 grid(1024 + 256 + 256);  // part0 + part1 + part2 slices
    dim3 block(TPB);
    pershom_kernel<<<grid, block, 0, stream>>>(
        h0, m0, h0e, m0e, h1e, m1e, c0, r0, c0e, r0e, c1e, r1e, out);
}